// Round 4
// baseline (663.218 us; speedup 1.0000x reference)
//
#include <hip/hip_runtime.h>
#include <math.h>

// B=4, N=4096, C=1024, KV=1024, H=4, Ch=Kh=256
// z = (path<<4) | (b<<2) | h  for 32-group stages.
// Chain: GT = Xm^T@Xn -> T = Wq@GT^T -> S = T@Wk^T (*1/32)
//        p = softmax(instnorm(S)) -> PT = WvT@p^T -> Mb = WoutR@PT^T -> O = X@Mb^T
// All MFMA staging uses global_load_lds w/ XOR-swizzled source chunks so the
// ds_read_b128 fragment reads are 2-way (free) instead of 8-way conflicted.

typedef __bf16 bf16x4 __attribute__((ext_vector_type(4)));
typedef __bf16 bf16x8 __attribute__((ext_vector_type(8)));
typedef float f32x4 __attribute__((ext_vector_type(4)));

__device__ inline void gl2lds16(const void* g, void* l) {
    __builtin_amdgcn_global_load_lds(
        (const __attribute__((address_space(1))) unsigned int*)g,
        (__attribute__((address_space(3))) unsigned int*)l, 16, 0, 0);
}

// ---------------- prep: transpose X -> XT bf16 (all 4), straight bf16 (emb_all/alld) ----
// grid (64 n-tiles, 16 c-tiles, 16 = input*4+b), block 256
__global__ __launch_bounds__(256) void prep_xt(
    const float* __restrict__ emb1, const float* __restrict__ emb_all,
    const float* __restrict__ embd1, const float* __restrict__ emb_alld,
    __bf16* __restrict__ XT, __bf16* __restrict__ Xb)
{
    __shared__ __bf16 Ts[64 * 72];
    const int in = blockIdx.z >> 2, b = blockIdx.z & 3;
    const float* srcs[4] = {emb1, emb_all, embd1, emb_alld};
    const float* src = srcs[in] + (long long)b * 4194304;
    const int n0 = blockIdx.x * 64, c0 = blockIdx.y * 64;
    const int t = threadIdx.x;
    const int r = t >> 4, c4 = (t & 15) * 4;

    float4 v[4];
#pragma unroll
    for (int rr = 0; rr < 4; ++rr) {
        int row = rr * 16 + r;
        v[rr] = *(const float4*)&src[(long long)(n0 + row) * 1024 + c0 + c4];
#pragma unroll
        for (int j = 0; j < 4; ++j)
            Ts[(c4 + j) * 72 + row] = (__bf16)(((const float*)&v[rr])[j]);
    }
    // straight bf16 for emb_all (in=1 -> slot0) / emb_alld (in=3 -> slot1)
    if (in & 1) {
        __bf16* dst = Xb + (long long)(in >> 1) * 16777216 + (long long)b * 4194304;
#pragma unroll
        for (int rr = 0; rr < 4; ++rr) {
            bf16x4 o = {(__bf16)v[rr].x, (__bf16)v[rr].y, (__bf16)v[rr].z, (__bf16)v[rr].w};
            *(bf16x4*)&dst[(long long)(n0 + rr * 16 + r) * 1024 + c0 + c4] = o;
        }
    }
    __syncthreads();
    __bf16* xt = XT + (long long)blockIdx.z * 4194304;   // [in*4+b][1024][4096]
#pragma unroll
    for (int rr = 0; rr < 2; ++rr) {
        int c = rr * 32 + (t >> 3), nch = (t & 7) * 8;
        bf16x8 o = *(const bf16x8*)&Ts[c * 72 + nch];
        *(bf16x8*)&xt[(long long)(c0 + c) * 4096 + n0 + nch] = o;
    }
}

// ---------------- prep: weights -> bf16 (+transpose/gather) ----------------
__global__ __launch_bounds__(256) void prep_w(
    const float* __restrict__ Wq, const float* __restrict__ Wqd,
    const float* __restrict__ Wk0, const float* __restrict__ Wv0,
    const float* __restrict__ Wkd0, const float* __restrict__ Wvd0,
    const float* __restrict__ Wout, const float* __restrict__ Woutd,
    __bf16* __restrict__ Wq_bf, __bf16* __restrict__ Wk_bf,
    __bf16* __restrict__ WvT_bf, __bf16* __restrict__ WoutR_bf)
{
    int id = blockIdx.x * 256 + threadIdx.x;
    if (id < 524288) {
        Wq_bf[id] = (__bf16)(id < 262144 ? Wq[id] : Wqd[id - 262144]);
    } else if (id < 655360) {
        int j = id - 524288;
        Wk_bf[j] = (__bf16)(j < 65536 ? Wkd0[j] : Wk0[j - 65536]);
    } else if (id < 786432) {
        int j = id - 655360;
        int p = j >> 16, r = (j >> 8) & 255, c2 = j & 255;
        const float* s = p ? Wv0 : Wvd0;
        WvT_bf[j] = (__bf16)s[c2 * 256 + r];
    } else if (id < 2883584) {
        int j = id - 786432;
        int p = j >> 20; int rem = j & 1048575; int h = rem >> 18; int oc = rem & 262143;
        int o = oc >> 8, c = oc & 255;
        const float* s = p ? Woutd : Wout;
        WoutR_bf[j] = (__bf16)s[o * 1024 + c * 4 + h];
    }
}

// ---------------- gram: NT MFMA on XT, 128x128 tile, split-K x2 ----------------
// grid (4 tiles, 2 ksplit, 32 z), block 256
__global__ __launch_bounds__(256) void gram_nt(
    const __bf16* __restrict__ XT, float* __restrict__ Gpart)
{
    __shared__ __bf16 As[128 * 32];
    __shared__ __bf16 Bs[128 * 32];

    const int z = blockIdx.z;
    const int path = z >> 4, b = (z >> 2) & 3, h = z & 3;
    const int inXm = path == 0 ? 3 : 1;   // emb_alld : emb_all  (m = k')
    const int inXn = path == 0 ? 0 : 2;   // emb1 : embd1        (n = c)
    const int ti = blockIdx.x >> 1, tj = blockIdx.x & 1;
    const __bf16* Ab = XT + (long long)(inXm * 4 + b) * 4194304 + (long long)(h * 256 + ti * 128) * 4096;
    const __bf16* Bb = XT + (long long)(inXn * 4 + b) * 4194304 + (long long)(h * 256 + tj * 128) * 4096;

    const int t = threadIdx.x;
    const int lane = t & 63, wave = t >> 6;
    const int wr = (wave >> 1) * 64, wc = (wave & 1) * 64;
    const int fm = lane & 15, fg = lane >> 4;
    const int key = (fm >> 1) & 3;
    const int srow = t >> 2;
    const int schunk = (t & 3) ^ ((t >> 3) & 3);

    const __bf16* ga0 = Ab + (long long)srow * 4096 + schunk * 8;
    const __bf16* ga1 = Ab + (long long)(64 + srow) * 4096 + schunk * 8;
    const __bf16* gb0 = Bb + (long long)srow * 4096 + schunk * 8;
    const __bf16* gb1 = Bb + (long long)(64 + srow) * 4096 + schunk * 8;
    __bf16* la0 = &As[t * 8];
    __bf16* la1 = &As[2048 + t * 8];
    __bf16* lb0 = &Bs[t * 8];
    __bf16* lb1 = &Bs[2048 + t * 8];

    f32x4 acc[4][4];
#pragma unroll
    for (int u = 0; u < 4; ++u)
#pragma unroll
        for (int v = 0; v < 4; ++v) acc[u][v] = (f32x4){0.f, 0.f, 0.f, 0.f};

    const int k0 = blockIdx.y * 2048;
    for (int kb = k0; kb < k0 + 2048; kb += 32) {
        __syncthreads();
        gl2lds16(ga0 + kb, la0);
        gl2lds16(ga1 + kb, la1);
        gl2lds16(gb0 + kb, lb0);
        gl2lds16(gb1 + kb, lb1);
        __syncthreads();

        bf16x8 af[4], bv[4];
#pragma unroll
        for (int mt = 0; mt < 4; ++mt)
            af[mt] = *(const bf16x8*)&As[(wr >> 6) * 2048 + (mt * 16 + fm) * 32 + (fg ^ key) * 8];
#pragma unroll
        for (int nt = 0; nt < 4; ++nt)
            bv[nt] = *(const bf16x8*)&Bs[(wc >> 6) * 2048 + (nt * 16 + fm) * 32 + (fg ^ key) * 8];
#pragma unroll
        for (int mt = 0; mt < 4; ++mt)
#pragma unroll
            for (int nt = 0; nt < 4; ++nt)
                acc[mt][nt] = __builtin_amdgcn_mfma_f32_16x16x32_bf16(af[mt], bv[nt], acc[mt][nt], 0, 0, 0);
    }

    float* Gp = Gpart + ((long long)blockIdx.y * 32 + z) * 65536;
    const int col = lane & 15, rq = (lane >> 4) * 4;
#pragma unroll
    for (int mt = 0; mt < 4; ++mt)
#pragma unroll
        for (int nt = 0; nt < 4; ++nt)
#pragma unroll
            for (int r = 0; r < 4; ++r)
                Gp[(ti * 128 + wr + mt * 16 + rq + r) * 256 + (tj * 128 + wc + nt * 16 + col)] = acc[mt][nt][r];
}

__global__ __launch_bounds__(256) void reduce2(const float* __restrict__ Gpart, __bf16* __restrict__ GT) {
    long long idx4 = (long long)blockIdx.x * 256 + threadIdx.x;   // < 524288
    float4 a = *(const float4*)&Gpart[idx4 * 4];
    float4 b = *(const float4*)&Gpart[2097152 + idx4 * 4];
    bf16x4 o;
    o[0] = (__bf16)(a.x + b.x);
    o[1] = (__bf16)(a.y + b.y);
    o[2] = (__bf16)(a.z + b.z);
    o[3] = (__bf16)(a.w + b.w);
    *(bf16x4*)&GT[idx4 * 4] = o;
}

// ---------------- generic NT MFMA: C[z] = alpha * A[z] @ B[z]^T (64x64 tile) ----------------
template <typename CT>
__global__ __launch_bounds__(256) void mfma_nt(
    const __bf16* __restrict__ A, const __bf16* __restrict__ B, CT* __restrict__ C,
    int mtiles, int K,
    long long a1, long long a2, long long a3,
    long long b1, long long b2, long long b3,
    long long c1, long long c2, long long c3,
    int cpitch, float alpha)
{
    __shared__ __bf16 As[64 * 32];
    __shared__ __bf16 Bs[64 * 32];
    const int z = blockIdx.y;
    const __bf16* Az = A + (long long)(z >> 4) * a1 + (long long)((z >> 2) & 3) * a2 + (long long)(z & 3) * a3;
    const __bf16* Bz = B + (long long)(z >> 4) * b1 + (long long)((z >> 2) & 3) * b2 + (long long)(z & 3) * b3;
    CT* Cz = C + (long long)(z >> 4) * c1 + (long long)((z >> 2) & 3) * c2 + (long long)(z & 3) * c3;

    const int tm = blockIdx.x % mtiles, tn = blockIdx.x / mtiles;
    const int t = threadIdx.x;
    const int lane = t & 63, wave = t >> 6;
    const int fm = lane & 15, fg = lane >> 4;
    const int key = (fm >> 1) & 3;
    const int srow = t >> 2;
    const int schunk = (t & 3) ^ ((t >> 3) & 3);

    const __bf16* ga = Az + (long long)(tm * 64 + srow) * K + schunk * 8;
    const __bf16* gb = Bz + (long long)(tn * 64 + srow) * K + schunk * 8;
    __bf16* la = &As[t * 8];
    __bf16* lb = &Bs[t * 8];

    f32x4 acc[4];
#pragma unroll
    for (int u = 0; u < 4; ++u) acc[u] = (f32x4){0.f, 0.f, 0.f, 0.f};

    for (int kb = 0; kb < K; kb += 32) {
        __syncthreads();
        gl2lds16(ga + kb, la);
        gl2lds16(gb + kb, lb);
        __syncthreads();
        bf16x8 bv = *(const bf16x8*)&Bs[(wave * 16 + fm) * 32 + (fg ^ key) * 8];
#pragma unroll
        for (int mt = 0; mt < 4; ++mt) {
            bf16x8 av = *(const bf16x8*)&As[(mt * 16 + fm) * 32 + (fg ^ key) * 8];
            acc[mt] = __builtin_amdgcn_mfma_f32_16x16x32_bf16(av, bv, acc[mt], 0, 0, 0);
        }
    }

    const int colc = tn * 64 + wave * 16 + fm;
    const int rq = fg * 4;
#pragma unroll
    for (int mt = 0; mt < 4; ++mt)
#pragma unroll
        for (int r = 0; r < 4; ++r) {
            int rowc = tm * 64 + mt * 16 + rq + r;
            Cz[(long long)rowc * cpitch + colc] = (CT)(acc[mt][r] * alpha);
        }
}

// ---------------- obig: O = X @ Mb^T (128x128, swizzled) ----------------
__global__ __launch_bounds__(256) void obig_mfma(
    const __bf16* __restrict__ Xb, const __bf16* __restrict__ Mb, float* __restrict__ out)
{
    __shared__ __bf16 As[128 * 32];
    __shared__ __bf16 Bs[128 * 32];

    const int z = blockIdx.z;
    const int path = z >> 2, b = z & 3;
    const __bf16* X = Xb + (path == 0 ? 16777216LL : 0LL) + (long long)b * 4194304;
    const __bf16* Bm = Mb + (long long)path * 4194304 + (long long)b * 1048576;
    float* Ob = out + (long long)path * 16777216 + (long long)b * 4194304;

    const int m0 = blockIdx.x * 128;
    const int o0 = blockIdx.y * 128;

    const int t = threadIdx.x;
    const int lane = t & 63, wave = t >> 6;
    const int wr = (wave >> 1) * 64, wc = (wave & 1) * 64;
    const int fm = lane & 15, fg = lane >> 4;
    const int key = (fm >> 1) & 3;
    const int srow = t >> 2;
    const int schunk = (t & 3) ^ ((t >> 3) & 3);

    const __bf16* ga0 = X + (long long)(m0 + srow) * 1024 + schunk * 8;
    const __bf16* ga1 = X + (long long)(m0 + 64 + srow) * 1024 + schunk * 8;
    const __bf16* gb0 = Bm + (long long)(o0 + srow) * 1024 + schunk * 8;
    const __bf16* gb1 = Bm + (long long)(o0 + 64 + srow) * 1024 + schunk * 8;
    __bf16* la0 = &As[t * 8];
    __bf16* la1 = &As[2048 + t * 8];
    __bf16* lb0 = &Bs[t * 8];
    __bf16* lb1 = &Bs[2048 + t * 8];

    f32x4 acc[4][4];
#pragma unroll
    for (int u = 0; u < 4; ++u)
#pragma unroll
        for (int v = 0; v < 4; ++v) acc[u][v] = (f32x4){0.f, 0.f, 0.f, 0.f};

    for (int kb = 0; kb < 1024; kb += 32) {
        __syncthreads();
        gl2lds16(ga0 + kb, la0);
        gl2lds16(ga1 + kb, la1);
        gl2lds16(gb0 + kb, lb0);
        gl2lds16(gb1 + kb, lb1);
        __syncthreads();

        bf16x8 af[4], bv[4];
#pragma unroll
        for (int mt = 0; mt < 4; ++mt)
            af[mt] = *(const bf16x8*)&As[(wr >> 6) * 2048 + (mt * 16 + fm) * 32 + (fg ^ key) * 8];
#pragma unroll
        for (int nt = 0; nt < 4; ++nt)
            bv[nt] = *(const bf16x8*)&Bs[(wc >> 6) * 2048 + (nt * 16 + fm) * 32 + (fg ^ key) * 8];
#pragma unroll
        for (int mt = 0; mt < 4; ++mt)
#pragma unroll
            for (int nt = 0; nt < 4; ++nt)
                acc[mt][nt] = __builtin_amdgcn_mfma_f32_16x16x32_bf16(af[mt], bv[nt], acc[mt][nt], 0, 0, 0);
    }

    const int col = lane & 15, rq = (lane >> 4) * 4;
#pragma unroll
    for (int mt = 0; mt < 4; ++mt)
#pragma unroll
        for (int nt = 0; nt < 4; ++nt)
#pragma unroll
            for (int r = 0; r < 4; ++r)
                Ob[(long long)(m0 + wr + mt * 16 + rq + r) * 1024 + (o0 + wc + nt * 16 + col)] = acc[mt][nt][r];
}

// ---------------- stats + softmax ----------------
__global__ __launch_bounds__(256) void stats_kernel(const float* __restrict__ S, float* __restrict__ st) {
    int pg = blockIdx.x;
    const float* s = S + (long long)pg * 65536;
    float sum = 0.f, sq = 0.f;
    for (int i = threadIdx.x; i < 65536; i += 256) {
        float v = s[i];
        sum += v;
        sq += v * v;
    }
#pragma unroll
    for (int off = 32; off; off >>= 1) {
        sum += __shfl_down(sum, off);
        sq  += __shfl_down(sq,  off);
    }
    __shared__ float r1[4], r2[4];
    int w = threadIdx.x >> 6;
    if ((threadIdx.x & 63) == 0) { r1[w] = sum; r2[w] = sq; }
    __syncthreads();
    if (threadIdx.x == 0) {
        float ts = r1[0] + r1[1] + r1[2] + r1[3];
        float tq = r2[0] + r2[1] + r2[2] + r2[3];
        float mean = ts * (1.0f / 65536.0f);
        float var = tq * (1.0f / 65536.0f) - mean * mean;
        st[pg * 2 + 0] = mean;
        st[pg * 2 + 1] = rsqrtf(var + 1e-5f);
    }
}

__global__ __launch_bounds__(256) void softmax_kernel(const float* __restrict__ S,
                                                      const float* __restrict__ st,
                                                      __bf16* __restrict__ p_bf) {
    int pg = blockIdx.y;
    int c = blockIdx.x;
    float mean = st[pg * 2 + 0], rstd = st[pg * 2 + 1];
    const float* row = S + (long long)pg * 65536 + c * 256;
    int t = threadIdx.x;
    float x = (row[t] - mean) * rstd;
    float m = x;
#pragma unroll
    for (int off = 32; off; off >>= 1) m = fmaxf(m, __shfl_down(m, off));
    __shared__ float r1[4], r2[4];
    int w = t >> 6;
    if ((t & 63) == 0) r1[w] = m;
    __syncthreads();
    m = fmaxf(fmaxf(r1[0], r1[1]), fmaxf(r1[2], r1[3]));
    float e = expf(x - m);
    float ssum = e;
#pragma unroll
    for (int off = 32; off; off >>= 1) ssum += __shfl_down(ssum, off);
    if ((t & 63) == 0) r2[w] = ssum;
    __syncthreads();
    ssum = r2[0] + r2[1] + r2[2] + r2[3];
    p_bf[(long long)pg * 65536 + c * 256 + t] = (__bf16)(e / ssum);
}

extern "C" void kernel_launch(void* const* d_in, const int* in_sizes, int n_in,
                              void* d_out, int out_size, void* d_ws, size_t ws_size,
                              hipStream_t stream) {
    const float* emb1     = (const float*)d_in[0];
    const float* emb_all  = (const float*)d_in[1];
    const float* embd1    = (const float*)d_in[2];
    const float* emb_alld = (const float*)d_in[3];
    const float* Wq    = (const float*)d_in[4];
    const float* Wqd   = (const float*)d_in[5];
    const float* Wk0   = (const float*)d_in[6];
    const float* Wv0   = (const float*)d_in[7];
    const float* Wkd0  = (const float*)d_in[8];
    const float* Wvd0  = (const float*)d_in[9];
    const float* Wout  = (const float*)d_in[10];
    const float* Woutd = (const float*)d_in[11];
    float* out = (float*)d_out;

    float* ws = (float*)d_ws;
    __bf16* XT_bf   = (__bf16*)ws;                    // [4 in][4 b][1024][4096] = 67,108,864 bf16
    __bf16* X_bf    = (__bf16*)(ws + 33554432);       // [2][4 b][4096][1024] = 33,554,432 bf16
    float*  Gpart   = ws + 50331648;                  // 4,194,304 fl (dead after reduce2)
    __bf16* Mb_bf   = (__bf16*)(ws + 50331648);       // 8,388,608 bf16 (aliases Gpart)
    __bf16* GT_bf   = (__bf16*)(ws + 54525952);       // 2,097,152 bf16
    __bf16* T_bf    = (__bf16*)(ws + 55574528);       // 2,097,152 bf16
    float*  S       = ws + 56623104;                  // 2,097,152 fl
    __bf16* p_bf    = (__bf16*)(ws + 58720256);       // 2,097,152 bf16
    __bf16* PT_bf   = (__bf16*)(ws + 59768832);       // 2,097,152 bf16
    __bf16* Wq_bf   = (__bf16*)(ws + 60817408);       // 524,288 bf16
    __bf16* Wk_bf   = (__bf16*)(ws + 61079552);       // 131,072 bf16
    __bf16* WvT_bf  = (__bf16*)(ws + 61145088);       // 131,072 bf16
    __bf16* WoutR_bf= (__bf16*)(ws + 61210624);       // 2,097,152 bf16
    float*  st      = ws + 62259200;                  // 64 fl -> total ~249 MB

    dim3 blk(256);

    // prep: transpose+cvt all X, straight bf16 for emb_all/emb_alld, weights
    prep_xt<<<dim3(64, 16, 16), blk, 0, stream>>>(emb1, emb_all, embd1, emb_alld, XT_bf, X_bf);
    prep_w<<<11264, blk, 0, stream>>>(Wq, Wqd, Wk0, Wv0, Wkd0, Wvd0, Wout, Woutd,
                                      Wq_bf, Wk_bf, WvT_bf, WoutR_bf);

    // GT = Xm^T @ Xn (NT on XT, split-K x2) + reduce -> bf16
    gram_nt<<<dim3(4, 2, 32), blk, 0, stream>>>(XT_bf, Gpart);
    reduce2<<<2048, blk, 0, stream>>>(Gpart, GT_bf);

    // T = Wq_h @ G
    mfma_nt<__bf16><<<dim3(16, 32), blk, 0, stream>>>(
        Wq_bf, GT_bf, T_bf, 4, 256,
        262144, 0, 65536,  1048576, 262144, 65536,  1048576, 262144, 65536, 256, 1.0f);
    // S = scale * T @ Wk'^T
    mfma_nt<float><<<dim3(16, 32), blk, 0, stream>>>(
        T_bf, Wk_bf, S, 4, 256,
        1048576, 262144, 65536,  65536, 0, 0,  1048576, 262144, 65536, 256, 0.03125f);

    stats_kernel<<<32, blk, 0, stream>>>(S, st);
    softmax_kernel<<<dim3(256, 32), blk, 0, stream>>>(S, st, p_bf);

    // PT = WvT @ p^T
    mfma_nt<__bf16><<<dim3(16, 32), blk, 0, stream>>>(
        WvT_bf, p_bf, PT_bf, 4, 256,
        65536, 0, 0,  1048576, 262144, 65536,  1048576, 262144, 65536, 256, 1.0f);
    // Mb = WoutR @ PT^T
    mfma_nt<__bf16><<<dim3(64, 32), blk, 0, stream>>>(
        WoutR_bf, PT_bf, Mb_bf, 16, 256,
        1048576, 0, 262144,  1048576, 262144, 65536,  4194304, 1048576, 256, 1024, 1.0f);

    // O = X @ Mb^T
    obig_mfma<<<dim3(32, 8, 8), blk, 0, stream>>>(X_bf, Mb_bf, out);
}